// Round 1
// 101.605 us; speedup vs baseline: 1.1155x; 1.1155x over previous
//
#include <hip/hip_runtime.h>
#include <hip/hip_bf16.h>

#define NSPLIT 16
#define BIGF 1e30f
#define MARGIN 0.3f
#define DK 128

typedef __attribute__((ext_vector_type(8))) short bf16x8;
typedef __attribute__((ext_vector_type(4))) float f32x4;

// workspace word offsets
#define WS_HIST 0                  // 1024 u32 label histogram
#define WS_HP   1024               // 8192 u32: max d2_pos bits (init 0)
#define WS_HN   (1024 + 8192)      // 8192 u32: max ~d2_neg bits (init 0 => min via complement)
#define WS_GSUM (1024 + 16384)     // f32 sum
#define WS_GCNT (WS_GSUM + 1)      // f32 cnt
#define WS_BCNT (WS_GSUM + 2)      // u32 block counter
#define WS_SQ   (WS_GSUM + 4)      // 8192 f32 squared norms (16B aligned)
#define WS_XB   (WS_SQ + 8192)     // bf16 copy of X, FRAGMENT-SWIZZLED (16B aligned)

// Fragment-swizzled bf16 layout of X:
//   xs[ (row>>4)*2048 + (k>>3)*128 + (row&15)*8 + (k&7) ]
// With this layout, an MFMA A/B fragment load for 16 rows/cols
// (lane = quad*16 + m16 reads elems k = s*32+quad*8 ..+7 of row/col base+m16)
// is 64 lanes reading ONE CONTIGUOUS 1 KB block:
//   base*128 + (s*4+quad)*128 + m16*8
// -> coalesced global_load_dwordx4 / conflict-free ds_read_b128,
// replacing the previous 16-cache-line-per-instruction column gathers.

// Kernel 1: swizzled bf16 copy + exact fp32 squared norms + label histogram.
__global__ void prep_kernel(const float* __restrict__ x, ushort* __restrict__ xs,
                            float* __restrict__ sq, unsigned* __restrict__ hist,
                            const int* __restrict__ lab, int N) {
    int wave = threadIdx.x >> 6;
    int lane = threadIdx.x & 63;
    int row = blockIdx.x * 4 + wave;
    if (row >= N) return;
    const float2* xr = (const float2*)(x + (size_t)row * DK);
    float2 v = xr[lane];              // elems 2*lane, 2*lane+1
    __hip_bfloat16 b0 = __float2bfloat16(v.x);
    __hip_bfloat16 b1 = __float2bfloat16(v.y);
    ushort2 st;
    st.x = *(ushort*)&b0;
    st.y = *(ushort*)&b1;
    // e = 2*lane: kc = lane>>2, e&7 = 2*(lane&3); both elems land in same kc chunk
    size_t off = (size_t)(row >> 4) * 2048 + (size_t)(lane >> 2) * 128
               + (size_t)(row & 15) * 8 + 2 * (lane & 3);
    *(ushort2*)(xs + off) = st;
    float s = v.x * v.x + v.y * v.y;
    #pragma unroll
    for (int o = 32; o > 0; o >>= 1) s += __shfl_xor(s, o, 64);
    if (lane == 0) {
        sq[row] = s;
        atomicAdd(&hist[lab[row]], 1u);
    }
}

// Kernel 2: fused bf16-MFMA dist^2 tile + masked max/min in t = sqb - 2*dot domain.
// Grid (N/128, NSPLIT); 4 waves per block, each owns a 64x64 quadrant.
// Column tile processed in two 32-col halves (h loop, unroll 1) so acc is 4x2
// f32x4 at a time -> VGPR stays ~128 -> 4 blocks/CU. launch_bounds min-waves
// kept at 2: higher re-caps the RF and spills accumulators (earlier regression).
__global__ __launch_bounds__(256, 2) void tile_kernel(
    const ushort* __restrict__ xs, const float* __restrict__ sq,
    const int* __restrict__ lab,
    unsigned* __restrict__ hp_bits, unsigned* __restrict__ hn_comp, int N)
{
    __shared__ ushort a_s[128 * DK];   // 32 KB, fragment-swizzled (8 groups x 2048)
    __shared__ int   laba_s[128];
    __shared__ float red_hp[128][2];
    __shared__ float red_hn[128][2];

    const int tid  = threadIdx.x;
    const int lane = tid & 63;
    const int wave = tid >> 6;
    const int m16  = lane & 15;
    const int quad = lane >> 4;
    const int rbase = blockIdx.x * 128;
    const int wrow = (wave >> 1) * 64;
    const int wcol = (wave & 1) * 64;

    // stage A tile: block's rows are one contiguous 32 KB region in xs
    {
        const bf16x8* srcv = (const bf16x8*)(xs + (size_t)rbase * DK);
        bf16x8* dstv = (bf16x8*)a_s;
        #pragma unroll
        for (int i = 0; i < 8; ++i)
            dstv[tid + i * 256] = srcv[tid + i * 256];
    }
    if (tid < 128) laba_s[tid] = lab[rbase + tid];
    __syncthreads();

    int rlab[4][4];
    #pragma unroll
    for (int mt = 0; mt < 4; ++mt)
        #pragma unroll
        for (int r = 0; r < 4; ++r)
            rlab[mt][r] = laba_s[wrow + mt * 16 + quad * 4 + r];

    float runhp[4][4], runhn[4][4];
    #pragma unroll
    for (int mt = 0; mt < 4; ++mt)
        #pragma unroll
        for (int r = 0; r < 4; ++r) { runhp[mt][r] = -BIGF; runhn[mt][r] = BIGF; }

    // loop-invariant per-lane fragment bases (contiguous-1KB pattern)
    const ushort* a_base = a_s + (size_t)((wave >> 1) * 4) * 2048
                         + (size_t)quad * 128 + (size_t)m16 * 8;

    const int cols_per_split = N / NSPLIT;   // 512
    const int cbegin = blockIdx.y * cols_per_split;

    for (int ci = 0; ci < cols_per_split; ci += 128) {
        const int cbase = cbegin + ci + wcol;
        const ushort* b_base = xs + (size_t)cbase * DK
                             + (size_t)quad * 128 + (size_t)m16 * 8;

        #pragma unroll 1   // keep h a real loop: prevents cross-half A-frag CSE (VGPR)
        for (int h = 0; h < 2; ++h) {
            float sqbv[2]; int lbv[2];
            #pragma unroll
            for (int j = 0; j < 2; ++j) {
                int colg = cbase + (h * 2 + j) * 16 + m16;
                sqbv[j] = sq[colg];
                lbv[j]  = lab[colg];
            }

            f32x4 acc[4][2];
            #pragma unroll
            for (int mt = 0; mt < 4; ++mt)
                #pragma unroll
                for (int j = 0; j < 2; ++j)
                    acc[mt][j] = (f32x4){0.f, 0.f, 0.f, 0.f};

            #pragma unroll
            for (int s = 0; s < 4; ++s) {
                bf16x8 bfr[2], afr[4];
                #pragma unroll
                for (int j = 0; j < 2; ++j)
                    bfr[j] = *(const bf16x8*)(b_base + (size_t)(h * 2 + j) * 2048 + s * 512);
                #pragma unroll
                for (int mt = 0; mt < 4; ++mt)
                    afr[mt] = *(const bf16x8*)(a_base + mt * 2048 + s * 512);
                #pragma unroll
                for (int mt = 0; mt < 4; ++mt)
                    #pragma unroll
                    for (int j = 0; j < 2; ++j)
                        acc[mt][j] = __builtin_amdgcn_mfma_f32_16x16x32_bf16(
                            afr[mt], bfr[j], acc[mt][j], 0, 0, 0);
            }

            #pragma unroll
            for (int j = 0; j < 2; ++j) {
                #pragma unroll
                for (int mt = 0; mt < 4; ++mt) {
                    #pragma unroll
                    for (int r = 0; r < 4; ++r) {
                        float t = fmaf(-2.0f, acc[mt][j][r], sqbv[j]);
                        bool same = (rlab[mt][r] == lbv[j]);
                        runhp[mt][r] = fmaxf(runhp[mt][r], same ? t : -BIGF);
                        runhn[mt][r] = fminf(runhn[mt][r], same ? BIGF : t);
                    }
                }
            }
        }
    }

    // reduce across the 16 m16-lanes sharing each row
    #pragma unroll
    for (int mt = 0; mt < 4; ++mt)
        #pragma unroll
        for (int r = 0; r < 4; ++r) {
            #pragma unroll
            for (int o = 8; o > 0; o >>= 1) {
                runhp[mt][r] = fmaxf(runhp[mt][r], __shfl_xor(runhp[mt][r], o, 16));
                runhn[mt][r] = fminf(runhn[mt][r], __shfl_xor(runhn[mt][r], o, 16));
            }
        }

    if (m16 == 0) {
        #pragma unroll
        for (int mt = 0; mt < 4; ++mt)
            #pragma unroll
            for (int r = 0; r < 4; ++r) {
                int rowl = wrow + mt * 16 + quad * 4 + r;
                red_hp[rowl][wave & 1] = runhp[mt][r];
                red_hn[rowl][wave & 1] = runhn[mt][r];
            }
    }
    __syncthreads();
    if (tid < 128) {
        float thp = fmaxf(red_hp[tid][0], red_hp[tid][1]);
        float thn = fminf(red_hn[tid][0], red_hn[tid][1]);
        float sqa = sq[rbase + tid];
        float d2p = fmaxf(sqa + thp, 0.0f);   // clamp == reference's max(d2,0)
        float d2n = fmaxf(sqa + thn, 0.0f);
        atomicMax(&hp_bits[rbase + tid], __float_as_uint(d2p));
        atomicMax(&hn_comp[rbase + tid], ~__float_as_uint(d2n));  // min via complement
    }
}

// Kernel 3: per-row loss + grid reduction; last block writes the scalar.
__global__ void finalize_kernel(const unsigned* __restrict__ hp_bits,
                                const unsigned* __restrict__ hn_comp,
                                const int* __restrict__ lab,
                                const unsigned* __restrict__ hist,
                                float* __restrict__ gsum, float* __restrict__ gcnt,
                                unsigned* __restrict__ bcount,
                                float* __restrict__ out, int N)
{
    __shared__ float s_sum[256];
    __shared__ float s_cnt[256];
    int tid = threadIdx.x;
    int row = blockIdx.x * 256 + tid;
    float loss = 0.0f, cv = 0.0f;
    if (row < N) {
        unsigned c = hist[lab[row]];
        bool valid = (c >= 2u) && (c < (unsigned)N);
        if (valid) {
            float dp = sqrtf(__uint_as_float(hp_bits[row]));
            float dn = sqrtf(__uint_as_float(~hn_comp[row]));
            loss = fmaxf(dp - dn + MARGIN, 0.0f);
            cv = 1.0f;
        }
    }
    s_sum[tid] = loss; s_cnt[tid] = cv;
    __syncthreads();
    for (int o = 128; o > 0; o >>= 1) {
        if (tid < o) { s_sum[tid] += s_sum[tid + o]; s_cnt[tid] += s_cnt[tid + o]; }
        __syncthreads();
    }
    if (tid == 0) {
        atomicAdd(gsum, s_sum[0]);
        atomicAdd(gcnt, s_cnt[0]);
        __threadfence();
        unsigned old = atomicAdd(bcount, 1u);
        if (old == gridDim.x - 1) {
            float s = atomicAdd(gsum, 0.0f);   // coherent read
            float c = atomicAdd(gcnt, 0.0f);
            out[0] = (c > 0.0f) ? s / c : 0.0f;
        }
    }
}

extern "C" void kernel_launch(void* const* d_in, const int* in_sizes, int n_in,
                              void* d_out, int out_size, void* d_ws, size_t ws_size,
                              hipStream_t stream) {
    const float* x = (const float*)d_in[0];
    const int* lab = (const int*)d_in[1];
    float* out = (float*)d_out;
    const int N = in_sizes[1];          // 8192

    unsigned* ws = (unsigned*)d_ws;
    unsigned* hist    = ws + WS_HIST;
    unsigned* hp_bits = ws + WS_HP;
    unsigned* hn_comp = ws + WS_HN;
    float* gsum = (float*)(ws + WS_GSUM);
    float* gcnt = (float*)(ws + WS_GCNT);
    unsigned* bcount = ws + WS_BCNT;
    float* sq = (float*)(ws + WS_SQ);
    ushort* xs = (ushort*)(ws + WS_XB);

    hipMemsetAsync(d_ws, 0, (size_t)WS_SQ * sizeof(unsigned), stream);
    prep_kernel<<<N / 4, 256, 0, stream>>>(x, xs, sq, hist, lab, N);
    dim3 grid(N / 128, NSPLIT);
    tile_kernel<<<grid, 256, 0, stream>>>(xs, sq, lab, hp_bits, hn_comp, N);
    finalize_kernel<<<N / 256, 256, 0, stream>>>(hp_bits, hn_comp, lab, hist,
                                                 gsum, gcnt, bcount, out, N);
}

// Round 2
// 97.350 us; speedup vs baseline: 1.1643x; 1.0437x over previous
//
#include <hip/hip_runtime.h>
#include <hip/hip_bf16.h>

#define NSPLIT 16
#define BIGF 1e30f
#define MARGIN 0.3f
#define DK 128

typedef __attribute__((ext_vector_type(8))) short bf16x8;
typedef __attribute__((ext_vector_type(4))) float f32x4;

// workspace word offsets
#define WS_HIST 0                  // 1024 u32 label histogram       (memset)
#define WS_GSUM 1024               // f32 sum                        (memset)
#define WS_GCNT 1025               // f32 cnt                        (memset)
#define WS_BCNT 1026               // u32 block counter              (memset)
#define WS_HP   1028               // 8192 u32 max d2_pos bits       (init by prep)
#define WS_HN   (WS_HP + 8192)     // 8192 u32 max ~d2_neg bits      (init by prep)
#define WS_SQ   (WS_HN + 8192)     // 8192 f32 squared norms         (written by prep)
#define WS_XB   (WS_SQ + 8192)     // bf16 copy of X, fragment-swizzled (16B aligned)
#define WS_ZERO_BYTES (1028 * 4)   // only hist + scalars need the memset now

// Fragment-swizzled bf16 layout of X:
//   xs[ (row>>4)*2048 + (k>>3)*128 + (row&15)*8 + (k&7) ]
// An MFMA A/B fragment load (16 rows, k = s*32+quad*8..+7) is 64 lanes reading
// ONE CONTIGUOUS 1KB block -> coalesced global_load_dwordx4 / conflict-free
// ds_read_b128. Linear in unit index n = grp*256 + kc*16 + rlq (16B units).

// Kernel 1: swizzled bf16 copy + exact fp32 squared norms + label histogram
// + zero-init of the per-row hp/hn atomics slots (covers each row exactly once).
// Each thread produces one contiguous 16B swizzled unit -> coalesced stores;
// the strided 32B reads are absorbed by L1/L2 (x is read once).
__global__ __launch_bounds__(256) void prep_kernel(
    const float* __restrict__ x, ushort* __restrict__ xs,
    float* __restrict__ sq, unsigned* __restrict__ hist,
    const int* __restrict__ lab,
    unsigned* __restrict__ hp_bits, unsigned* __restrict__ hn_comp, int N)
{
    __shared__ float part[32][17];     // [+1 pad: conflict-free column sum]
    const int tid = threadIdx.x;
    const int rbase = blockIdx.x * 32;
    const int rlq = tid & 15;          // row within 16-row group
    const int kc  = tid >> 4;          // 8-elem k-chunk
    bf16x8* outv = (bf16x8*)(xs + (size_t)rbase * DK);

    #pragma unroll
    for (int g = 0; g < 2; ++g) {
        int row = rbase + g * 16 + rlq;
        const float4* p = (const float4*)(x + (size_t)row * DK + kc * 8);
        float4 u = p[0], v = p[1];
        float f[8] = {u.x, u.y, u.z, u.w, v.x, v.y, v.z, v.w};
        union { bf16x8 v8; ushort us[8]; } o;
        float ps = 0.0f;
        #pragma unroll
        for (int e = 0; e < 8; ++e) {
            __hip_bfloat16 b = __float2bfloat16(f[e]);
            o.us[e] = *(ushort*)&b;
            ps += f[e] * f[e];
        }
        outv[g * 256 + tid] = o.v8;            // coalesced 16B stores
        part[g * 16 + rlq][kc] = ps;
    }
    __syncthreads();
    if (tid < 32) {
        float s = 0.0f;
        #pragma unroll
        for (int k = 0; k < 16; ++k) s += part[tid][k];   // deterministic order
        int row = rbase + tid;
        sq[row] = s;
        hp_bits[row] = 0u;                      // max(d2p>=0) domain: 0 is identity
        hn_comp[row] = 0u;                      // ~bits identity for min-complement
        atomicAdd(&hist[lab[row]], 1u);
    }
}

// ---- tile_kernel helpers ------------------------------------------------

#define ZERO_ACC(ACC)                                                     \
    _Pragma("unroll")                                                     \
    for (int mt = 0; mt < 4; ++mt)                                        \
        _Pragma("unroll")                                                 \
        for (int j = 0; j < 2; ++j)                                       \
            ACC[mt][j] = (f32x4){0.f, 0.f, 0.f, 0.f};

#define MFMA_HALF(ACC, B)                                                 \
    _Pragma("unroll")                                                     \
    for (int s = 0; s < 4; ++s) {                                         \
        bf16x8 afr[4];                                                    \
        _Pragma("unroll")                                                 \
        for (int mt = 0; mt < 4; ++mt)                                    \
            afr[mt] = *(const bf16x8*)(a_base + mt * 2048 + s * 512);     \
        _Pragma("unroll")                                                 \
        for (int mt = 0; mt < 4; ++mt)                                    \
            _Pragma("unroll")                                             \
            for (int j = 0; j < 2; ++j)                                   \
                ACC[mt][j] = __builtin_amdgcn_mfma_f32_16x16x32_bf16(     \
                    afr[mt], B[j][s], ACC[mt][j], 0, 0, 0);               \
    }

// rlab comes from LDS (int4 broadcast read) instead of 16 persistent VGPRs;
// fmaxf(fmaxf(.,.),.) fuses to v_max3_f32 / v_min3_f32.
#define EPI_HALF(ACC, SQB, LB)                                            \
    _Pragma("unroll")                                                     \
    for (int mt = 0; mt < 4; ++mt) {                                      \
        int4 rl4 = *(const int4*)&laba_s[wrow + mt * 16 + quad * 4];      \
        const int rla[4] = {rl4.x, rl4.y, rl4.z, rl4.w};                  \
        _Pragma("unroll")                                                 \
        for (int r = 0; r < 4; ++r) {                                     \
            float t0 = fmaf(-2.0f, ACC[mt][0][r], SQB[0]);                \
            float t1 = fmaf(-2.0f, ACC[mt][1][r], SQB[1]);                \
            bool s0 = (rla[r] == LB[0]);                                  \
            bool s1 = (rla[r] == LB[1]);                                  \
            float cp0 = s0 ? t0 : -BIGF;                                  \
            float cp1 = s1 ? t1 : -BIGF;                                  \
            runhp[mt][r] = fmaxf(fmaxf(runhp[mt][r], cp0), cp1);          \
            float cn0 = s0 ? BIGF : t0;                                   \
            float cn1 = s1 ? BIGF : t1;                                   \
            runhn[mt][r] = fminf(fminf(runhn[mt][r], cn0), cn1);          \
        }                                                                 \
    }

// Kernel 2: fused bf16-MFMA dist^2 tile + masked max/min in t = sqb - 2*dot.
// Grid (N/128, NSPLIT); 4 waves per block, each a 64x64 quadrant, processed
// as two 64x32 halves. Half-1's B loads are issued BEFORE half-0's epilogue
// (b0 regs are dead after its MFMAs) so the ~200cy L2 latency hides under
// ~380cy of epilogue VALU. Peak live ~ runh32+acc32+b[next]32+misc -> <=128
// VGPR -> 4 waves/SIMD, 4 blocks/CU, 1024 blocks = one full residency wave.
__global__ __launch_bounds__(256, 2) void tile_kernel(
    const ushort* __restrict__ xs, const float* __restrict__ sq,
    const int* __restrict__ lab,
    unsigned* __restrict__ hp_bits, unsigned* __restrict__ hn_comp, int N)
{
    __shared__ ushort a_s[128 * DK];   // 32 KB, fragment-swizzled
    __shared__ int   laba_s[128];
    __shared__ float red_hp[128][2];
    __shared__ float red_hn[128][2];

    const int tid  = threadIdx.x;
    const int lane = tid & 63;
    const int wave = tid >> 6;
    const int m16  = lane & 15;
    const int quad = lane >> 4;
    const int rbase = blockIdx.x * 128;
    const int wrow = (wave >> 1) * 64;
    const int wcol = (wave & 1) * 64;

    // stage A tile: one contiguous 32 KB region in xs
    {
        const bf16x8* srcv = (const bf16x8*)(xs + (size_t)rbase * DK);
        bf16x8* dstv = (bf16x8*)a_s;
        #pragma unroll
        for (int i = 0; i < 8; ++i)
            dstv[tid + i * 256] = srcv[tid + i * 256];
    }
    if (tid < 128) laba_s[tid] = lab[rbase + tid];
    __syncthreads();

    float runhp[4][4], runhn[4][4];
    #pragma unroll
    for (int mt = 0; mt < 4; ++mt)
        #pragma unroll
        for (int r = 0; r < 4; ++r) { runhp[mt][r] = -BIGF; runhn[mt][r] = BIGF; }

    // loop-invariant fragment bases (contiguous-1KB pattern)
    const ushort* a_base = a_s + wrow * DK + quad * 128 + m16 * 8;

    const int cols_per_split = N / NSPLIT;   // 512
    const int cbegin = blockIdx.y * cols_per_split + wcol;

    // per-lane 32-bit voffsets (ushort units) for the 4 col16-chunks;
    // s*512-elem deltas fold into the 13-bit imm offset of the load.
    unsigned voff[4];
    #pragma unroll
    for (int c = 0; c < 4; ++c)
        voff[c] = (unsigned)(cbegin + c * 16) * DK + quad * 128 + m16 * 8;

    #pragma unroll 1
    for (int ci = 0; ci < cols_per_split; ci += 128) {
        // ---- B loads, half 0 (chunks 0,1)
        bf16x8 b0[2][4];
        #pragma unroll
        for (int j = 0; j < 2; ++j)
            #pragma unroll
            for (int s = 0; s < 4; ++s)
                b0[j][s] = *(const bf16x8*)(xs + voff[j] + s * 512);
        float sqb0[2]; int lb0[2];
        #pragma unroll
        for (int j = 0; j < 2; ++j) {
            int colg = cbegin + ci + j * 16 + m16;
            sqb0[j] = sq[colg]; lb0[j] = lab[colg];
        }

        f32x4 acc[4][2];
        ZERO_ACC(acc);
        MFMA_HALF(acc, b0);

        // ---- prefetch B half 1 (chunks 2,3) BEFORE epilogue 0
        bf16x8 b1[2][4];
        #pragma unroll
        for (int j = 0; j < 2; ++j)
            #pragma unroll
            for (int s = 0; s < 4; ++s)
                b1[j][s] = *(const bf16x8*)(xs + voff[2 + j] + s * 512);
        float sqb1[2]; int lb1[2];
        #pragma unroll
        for (int j = 0; j < 2; ++j) {
            int colg = cbegin + ci + (2 + j) * 16 + m16;
            sqb1[j] = sq[colg]; lb1[j] = lab[colg];
        }

        // ---- epilogue half 0 (VALU; overlaps the in-flight b1 loads)
        EPI_HALF(acc, sqb0, lb0);

        // ---- half 1
        ZERO_ACC(acc);
        MFMA_HALF(acc, b1);
        EPI_HALF(acc, sqb1, lb1);

        #pragma unroll
        for (int c = 0; c < 4; ++c) voff[c] += 128 * DK;
    }

    // reduce across the 16 m16-lanes sharing each row
    #pragma unroll
    for (int mt = 0; mt < 4; ++mt)
        #pragma unroll
        for (int r = 0; r < 4; ++r) {
            #pragma unroll
            for (int o = 8; o > 0; o >>= 1) {
                runhp[mt][r] = fmaxf(runhp[mt][r], __shfl_xor(runhp[mt][r], o, 16));
                runhn[mt][r] = fminf(runhn[mt][r], __shfl_xor(runhn[mt][r], o, 16));
            }
        }

    if (m16 == 0) {
        #pragma unroll
        for (int mt = 0; mt < 4; ++mt)
            #pragma unroll
            for (int r = 0; r < 4; ++r) {
                int rowl = wrow + mt * 16 + quad * 4 + r;
                red_hp[rowl][wave & 1] = runhp[mt][r];
                red_hn[rowl][wave & 1] = runhn[mt][r];
            }
    }
    __syncthreads();
    if (tid < 128) {
        float thp = fmaxf(red_hp[tid][0], red_hp[tid][1]);
        float thn = fminf(red_hn[tid][0], red_hn[tid][1]);
        float sqa = sq[rbase + tid];
        float d2p = fmaxf(sqa + thp, 0.0f);   // clamp == reference's max(d2,0)
        float d2n = fmaxf(sqa + thn, 0.0f);
        atomicMax(&hp_bits[rbase + tid], __float_as_uint(d2p));
        atomicMax(&hn_comp[rbase + tid], ~__float_as_uint(d2n));  // min via complement
    }
}

// Kernel 3: per-row loss + grid reduction; last block writes the scalar.
__global__ void finalize_kernel(const unsigned* __restrict__ hp_bits,
                                const unsigned* __restrict__ hn_comp,
                                const int* __restrict__ lab,
                                const unsigned* __restrict__ hist,
                                float* __restrict__ gsum, float* __restrict__ gcnt,
                                unsigned* __restrict__ bcount,
                                float* __restrict__ out, int N)
{
    __shared__ float s_sum[256];
    __shared__ float s_cnt[256];
    int tid = threadIdx.x;
    int row = blockIdx.x * 256 + tid;
    float loss = 0.0f, cv = 0.0f;
    if (row < N) {
        unsigned c = hist[lab[row]];
        bool valid = (c >= 2u) && (c < (unsigned)N);
        if (valid) {
            float dp = sqrtf(__uint_as_float(hp_bits[row]));
            float dn = sqrtf(__uint_as_float(~hn_comp[row]));
            loss = fmaxf(dp - dn + MARGIN, 0.0f);
            cv = 1.0f;
        }
    }
    s_sum[tid] = loss; s_cnt[tid] = cv;
    __syncthreads();
    for (int o = 128; o > 0; o >>= 1) {
        if (tid < o) { s_sum[tid] += s_sum[tid + o]; s_cnt[tid] += s_cnt[tid + o]; }
        __syncthreads();
    }
    if (tid == 0) {
        atomicAdd(gsum, s_sum[0]);
        atomicAdd(gcnt, s_cnt[0]);
        __threadfence();
        unsigned old = atomicAdd(bcount, 1u);
        if (old == gridDim.x - 1) {
            float s = atomicAdd(gsum, 0.0f);   // coherent read
            float c = atomicAdd(gcnt, 0.0f);
            out[0] = (c > 0.0f) ? s / c : 0.0f;
        }
    }
}

extern "C" void kernel_launch(void* const* d_in, const int* in_sizes, int n_in,
                              void* d_out, int out_size, void* d_ws, size_t ws_size,
                              hipStream_t stream) {
    const float* x = (const float*)d_in[0];
    const int* lab = (const int*)d_in[1];
    float* out = (float*)d_out;
    const int N = in_sizes[1];          // 8192

    unsigned* ws = (unsigned*)d_ws;
    unsigned* hist    = ws + WS_HIST;
    float* gsum = (float*)(ws + WS_GSUM);
    float* gcnt = (float*)(ws + WS_GCNT);
    unsigned* bcount = ws + WS_BCNT;
    unsigned* hp_bits = ws + WS_HP;
    unsigned* hn_comp = ws + WS_HN;
    float* sq = (float*)(ws + WS_SQ);
    ushort* xs = (ushort*)(ws + WS_XB);

    hipMemsetAsync(d_ws, 0, (size_t)WS_ZERO_BYTES, stream);
    prep_kernel<<<N / 32, 256, 0, stream>>>(x, xs, sq, hist, lab, hp_bits, hn_comp, N);
    dim3 grid(N / 128, NSPLIT);
    tile_kernel<<<grid, 256, 0, stream>>>(xs, sq, lab, hp_bits, hn_comp, N);
    finalize_kernel<<<N / 256, 256, 0, stream>>>(hp_bits, hn_comp, lab, hist,
                                                 gsum, gcnt, bcount, out, N);
}

// Round 4
// 92.968 us; speedup vs baseline: 1.2192x; 1.0471x over previous
//
#include <hip/hip_runtime.h>
#include <hip/hip_bf16.h>

#define NSPLIT 16
#define BIGF 1e30f
#define MARGIN 0.3f
#define DK 128

typedef __attribute__((ext_vector_type(8))) short bf16x8;
typedef __attribute__((ext_vector_type(4))) float f32x4;

// workspace word offsets
#define WS_HIST 0                  // 1024 u32 label histogram       (memset)
#define WS_GSUM 1024               // f32 sum                        (memset)
#define WS_GCNT 1025               // f32 cnt                        (memset)
#define WS_BCNT 1026               // u32 block counter              (memset)
#define WS_HP   1028               // 8192 u32 max d2_pos bits       (init by prep)
#define WS_HN   (WS_HP + 8192)     // 8192 u32 max ~d2_neg bits      (init by prep)
#define WS_SQ   (WS_HN + 8192)     // 8192 f32 squared norms         (written by prep)
#define WS_XB   (WS_SQ + 8192)     // bf16 copy of X, fragment-swizzled (16B aligned)
#define WS_ZERO_BYTES (1028 * 4)   // only hist + scalars need the memset

// Fragment-swizzled bf16 layout of X:
//   xs[ (row>>4)*2048 + (k>>3)*128 + (row&15)*8 + (k&7) ]
// An MFMA A/B fragment load (16 rows, k = s*32+quad*8..+7) is 64 lanes reading
// ONE CONTIGUOUS 1KB block -> coalesced global_load_dwordx4 / conflict-free
// ds_read_b128.

// Kernel 1: swizzled bf16 copy + fp32 squared norms + label histogram
// + zero-init of the per-row hp/hn atomics slots.
// Lane mapping kc = tid&15: READS are row-contiguous (coalesced); the 16B
// swizzled stores scatter within a 4KB region (write-combined, one-time 2MB).
__global__ __launch_bounds__(256) void prep_kernel(
    const float* __restrict__ x, ushort* __restrict__ xs,
    float* __restrict__ sq, unsigned* __restrict__ hist,
    const int* __restrict__ lab,
    unsigned* __restrict__ hp_bits, unsigned* __restrict__ hn_comp, int N)
{
    const int tid = threadIdx.x;
    const int rbase = blockIdx.x * 32;
    const int rl = tid >> 4;           // row within 16-row group (0..15)
    const int kc = tid & 15;           // 8-elem k-chunk (0..15)

    #pragma unroll
    for (int g = 0; g < 2; ++g) {
        int row = rbase + g * 16 + rl;
        const float4* p = (const float4*)(x + (size_t)row * DK + kc * 8);
        float4 u = p[0], v = p[1];
        float f[8] = {u.x, u.y, u.z, u.w, v.x, v.y, v.z, v.w};
        union { bf16x8 v8; ushort us[8]; } o;
        float ps = 0.0f;
        #pragma unroll
        for (int e = 0; e < 8; ++e) {
            __hip_bfloat16 b = __float2bfloat16(f[e]);
            o.us[e] = *(ushort*)&b;
            ps += f[e] * f[e];
        }
        // 16B unit index: (row>>4)*256 + kc*16 + (row&15)
        ((bf16x8*)xs)[(size_t)(row >> 4) * 256 + kc * 16 + rl] = o.v8;
        // lanes of one row are contiguous (tid = rl*16 + kc): width-16 butterfly
        #pragma unroll
        for (int o2 = 8; o2 > 0; o2 >>= 1) ps += __shfl_xor(ps, o2, 16);
        if (kc == 0) {
            sq[row] = ps;
            hp_bits[row] = 0u;             // identity for max(d2p>=0)
            hn_comp[row] = 0u;             // ~bits identity for min-complement
            atomicAdd(&hist[lab[row]], 1u);
        }
    }
}

// ---- tile_kernel helpers ------------------------------------------------

// MFMA over one 64x32 half; s=0 uses C=0 (no explicit acc zeroing pass).
#define MFMA_HALF_INIT(ACC, B)                                            \
    _Pragma("unroll")                                                     \
    for (int s = 0; s < 4; ++s) {                                         \
        bf16x8 afr[4];                                                    \
        _Pragma("unroll")                                                 \
        for (int mt = 0; mt < 4; ++mt)                                    \
            afr[mt] = *(const bf16x8*)(a_base + mt * 2048 + s * 512);     \
        _Pragma("unroll")                                                 \
        for (int mt = 0; mt < 4; ++mt)                                    \
            _Pragma("unroll")                                             \
            for (int j = 0; j < 2; ++j)                                   \
                ACC[mt][j] = __builtin_amdgcn_mfma_f32_16x16x32_bf16(     \
                    afr[mt], B[j][s],                                     \
                    (s == 0) ? (f32x4){0.f, 0.f, 0.f, 0.f} : ACC[mt][j],  \
                    0, 0, 0);                                             \
    }

// rlab from LDS (int4 broadcast); fmaxf(fmaxf(.,.),.) fuses to v_max3/min3.
#define EPI_HALF(ACC, SQB, LB)                                            \
    _Pragma("unroll")                                                     \
    for (int mt = 0; mt < 4; ++mt) {                                      \
        int4 rl4 = *(const int4*)&laba_s[wrow + mt * 16 + quad * 4];      \
        const int rla[4] = {rl4.x, rl4.y, rl4.z, rl4.w};                  \
        _Pragma("unroll")                                                 \
        for (int r = 0; r < 4; ++r) {                                     \
            float t0 = fmaf(-2.0f, ACC[mt][0][r], SQB[0]);                \
            float t1 = fmaf(-2.0f, ACC[mt][1][r], SQB[1]);                \
            bool s0 = (rla[r] == LB[0]);                                  \
            bool s1 = (rla[r] == LB[1]);                                  \
            float cp0 = s0 ? t0 : -BIGF;                                  \
            float cp1 = s1 ? t1 : -BIGF;                                  \
            runhp[mt][r] = fmaxf(fmaxf(runhp[mt][r], cp0), cp1);          \
            float cn0 = s0 ? BIGF : t0;                                   \
            float cn1 = s1 ? BIGF : t1;                                   \
            runhn[mt][r] = fminf(fminf(runhn[mt][r], cn0), cn1);          \
        }                                                                 \
    }

#define LOAD_HALF(B, SQB, LB, CHUNK0, CIN)                                \
    _Pragma("unroll")                                                     \
    for (int j = 0; j < 2; ++j) {                                         \
        _Pragma("unroll")                                                 \
        for (int s = 0; s < 4; ++s)                                       \
            B[j][s] = *(const bf16x8*)(xs + voff0                         \
                       + (unsigned)(CIN) * DK + (CHUNK0 + j) * 2048       \
                       + s * 512);                                        \
        int colg = cbegin + (CIN) + (CHUNK0 + j) * 16 + m16;              \
        SQB[j] = sq[colg];  LB[j] = lab[colg];                            \
    }

// Kernel 2: fused bf16-MFMA dist^2 tile + masked max/min in t = sqb - 2*dot.
// Grid (N/128, NSPLIT); 4 waves, each a 64x64 quadrant as two 64x32 halves.
// Uniform steady-state pipeline per half: MFMA(cur) -> issue loads(next half)
// -> EPI(cur). Every B load has ~EPI(320cy)+MFMA-issue of slack before its
// consumer, including across the ci boundary (clamped redundant prefetch on
// the last iteration). Only ONE 32-reg B buffer is live at any point (b0 dies
// at MFMA0 before its refill; b1 dies at MFMA1) -> ~128 VGPR, 4 waves/SIMD,
// 4 blocks/CU, 1024 blocks = one full residency wave.
__global__ __launch_bounds__(256, 2) void tile_kernel(
    const ushort* __restrict__ xs, const float* __restrict__ sq,
    const int* __restrict__ lab,
    unsigned* __restrict__ hp_bits, unsigned* __restrict__ hn_comp, int N)
{
    __shared__ ushort a_s[128 * DK];   // 32 KB, fragment-swizzled
    __shared__ int   laba_s[128];
    __shared__ float red_hp[128][2];
    __shared__ float red_hn[128][2];

    const int tid  = threadIdx.x;
    const int lane = tid & 63;
    const int wave = tid >> 6;
    const int m16  = lane & 15;
    const int quad = lane >> 4;
    const int rbase = blockIdx.x * 128;
    const int wrow = (wave >> 1) * 64;
    const int wcol = (wave & 1) * 64;

    // stage A tile: one contiguous 32 KB region in xs
    {
        const bf16x8* srcv = (const bf16x8*)(xs + (size_t)rbase * DK);
        bf16x8* dstv = (bf16x8*)a_s;
        #pragma unroll
        for (int i = 0; i < 8; ++i)
            dstv[tid + i * 256] = srcv[tid + i * 256];
    }
    if (tid < 128) laba_s[tid] = lab[rbase + tid];

    const int cols_per_split = N / NSPLIT;   // 512
    const int cbegin = blockIdx.y * cols_per_split + wcol;
    const unsigned voff0 = (unsigned)cbegin * DK + quad * 128 + m16 * 8;

    // prologue: prefetch half 0 of ci=0 before the barrier (latency overlaps
    // the barrier's vmcnt drain of the A-stage)
    bf16x8 b0[2][4], b1[2][4];
    float sqb0[2], sqb1[2]; int lb0[2], lb1[2];
    LOAD_HALF(b0, sqb0, lb0, 0, 0);

    __syncthreads();

    float runhp[4][4], runhn[4][4];
    #pragma unroll
    for (int mt = 0; mt < 4; ++mt)
        #pragma unroll
        for (int r = 0; r < 4; ++r) { runhp[mt][r] = -BIGF; runhn[mt][r] = BIGF; }

    const ushort* a_base = a_s + wrow * DK + quad * 128 + m16 * 8;

    #pragma unroll 1
    for (int ci = 0; ci < cols_per_split; ci += 128) {
        f32x4 acc[4][2];

        // ---- half 0: MFMA on preloaded b0
        MFMA_HALF_INIT(acc, b0);
        // issue half-1 loads (b0 regs dead; b1 hides under EPI0)
        LOAD_HALF(b1, sqb1, lb1, 2, ci);
        EPI_HALF(acc, sqb0, lb0);

        // ---- half 1
        MFMA_HALF_INIT(acc, b1);
        // issue next-iteration half-0 loads (clamped on last iter: redundant,
        // unconsumed — keeps the schedule branch-uniform)
        {
            int cin = (ci + 128 < cols_per_split) ? (ci + 128) : ci;
            LOAD_HALF(b0, sqb0, lb0, 0, cin);
        }
        EPI_HALF(acc, sqb1, lb1);
    }

    // reduce across the 16 m16-lanes sharing each row
    #pragma unroll
    for (int mt = 0; mt < 4; ++mt)
        #pragma unroll
        for (int r = 0; r < 4; ++r) {
            #pragma unroll
            for (int o = 8; o > 0; o >>= 1) {
                runhp[mt][r] = fmaxf(runhp[mt][r], __shfl_xor(runhp[mt][r], o, 16));
                runhn[mt][r] = fminf(runhn[mt][r], __shfl_xor(runhn[mt][r], o, 16));
            }
        }

    if (m16 == 0) {
        #pragma unroll
        for (int mt = 0; mt < 4; ++mt)
            #pragma unroll
            for (int r = 0; r < 4; ++r) {
                int rowl = wrow + mt * 16 + quad * 4 + r;
                red_hp[rowl][wave & 1] = runhp[mt][r];
                red_hn[rowl][wave & 1] = runhn[mt][r];
            }
    }
    __syncthreads();
    if (tid < 128) {
        float thp = fmaxf(red_hp[tid][0], red_hp[tid][1]);
        float thn = fminf(red_hn[tid][0], red_hn[tid][1]);
        float sqa = sq[rbase + tid];
        float d2p = fmaxf(sqa + thp, 0.0f);   // clamp == reference's max(d2,0)
        float d2n = fmaxf(sqa + thn, 0.0f);
        atomicMax(&hp_bits[rbase + tid], __float_as_uint(d2p));
        atomicMax(&hn_comp[rbase + tid], ~__float_as_uint(d2n));  // min via complement
    }
}

// Kernel 3: per-row loss + grid reduction; last block writes the scalar.
__global__ void finalize_kernel(const unsigned* __restrict__ hp_bits,
                                const unsigned* __restrict__ hn_comp,
                                const int* __restrict__ lab,
                                const unsigned* __restrict__ hist,
                                float* __restrict__ gsum, float* __restrict__ gcnt,
                                unsigned* __restrict__ bcount,
                                float* __restrict__ out, int N)
{
    __shared__ float s_sum[256];
    __shared__ float s_cnt[256];
    int tid = threadIdx.x;
    int row = blockIdx.x * 256 + tid;
    float loss = 0.0f, cv = 0.0f;
    if (row < N) {
        unsigned c = hist[lab[row]];
        bool valid = (c >= 2u) && (c < (unsigned)N);
        if (valid) {
            float dp = sqrtf(__uint_as_float(hp_bits[row]));
            float dn = sqrtf(__uint_as_float(~hn_comp[row]));
            loss = fmaxf(dp - dn + MARGIN, 0.0f);
            cv = 1.0f;
        }
    }
    s_sum[tid] = loss; s_cnt[tid] = cv;
    __syncthreads();
    for (int o = 128; o > 0; o >>= 1) {
        if (tid < o) { s_sum[tid] += s_sum[tid + o]; s_cnt[tid] += s_cnt[tid + o]; }
        __syncthreads();
    }
    if (tid == 0) {
        atomicAdd(gsum, s_sum[0]);
        atomicAdd(gcnt, s_cnt[0]);
        __threadfence();
        unsigned old = atomicAdd(bcount, 1u);
        if (old == gridDim.x - 1) {
            float s = atomicAdd(gsum, 0.0f);   // coherent read
            float c = atomicAdd(gcnt, 0.0f);
            out[0] = (c > 0.0f) ? s / c : 0.0f;
        }
    }
}

extern "C" void kernel_launch(void* const* d_in, const int* in_sizes, int n_in,
                              void* d_out, int out_size, void* d_ws, size_t ws_size,
                              hipStream_t stream) {
    const float* x = (const float*)d_in[0];
    const int* lab = (const int*)d_in[1];
    float* out = (float*)d_out;
    const int N = in_sizes[1];          // 8192

    unsigned* ws = (unsigned*)d_ws;
    unsigned* hist    = ws + WS_HIST;
    float* gsum = (float*)(ws + WS_GSUM);
    float* gcnt = (float*)(ws + WS_GCNT);
    unsigned* bcount = ws + WS_BCNT;
    unsigned* hp_bits = ws + WS_HP;
    unsigned* hn_comp = ws + WS_HN;
    float* sq = (float*)(ws + WS_SQ);
    ushort* xs = (ushort*)(ws + WS_XB);

    hipMemsetAsync(d_ws, 0, (size_t)WS_ZERO_BYTES, stream);
    prep_kernel<<<N / 32, 256, 0, stream>>>(x, xs, sq, hist, lab, hp_bits, hn_comp, N);
    dim3 grid(N / 128, NSPLIT);
    tile_kernel<<<grid, 256, 0, stream>>>(xs, sq, lab, hp_bits, hn_comp, N);
    finalize_kernel<<<N / 256, 256, 0, stream>>>(hp_bits, hn_comp, lab, hist,
                                                 gsum, gcnt, bcount, out, N);
}

// Round 5
// 92.136 us; speedup vs baseline: 1.2302x; 1.0090x over previous
//
#include <hip/hip_runtime.h>
#include <hip/hip_bf16.h>

#define NSPLIT 16
#define BIGF 1e30f
#define MARGIN 0.3f
#define DK 128

typedef __attribute__((ext_vector_type(8))) short bf16x8;
typedef __attribute__((ext_vector_type(4))) float f32x4;

// workspace word offsets
#define WS_HIST 0                  // 1024 u32 label histogram       (memset)
#define WS_GSUM 1024               // f32 sum                        (memset)
#define WS_GCNT 1025               // f32 cnt                        (memset)
#define WS_BCNT 1026               // u32 block counter              (memset)
#define WS_HP   1028               // 8192 u32 max d2_pos bits       (init by prep)
#define WS_HN   (WS_HP + 8192)     // 8192 u32 max ~d2_neg bits      (init by prep)
#define WS_SQ   (WS_HN + 8192)     // 8192 f32 squared norms         (written by prep)
#define WS_XB   (WS_SQ + 8192)     // bf16 copy of X, fragment-swizzled (16B aligned)
#define WS_ZERO_BYTES (1028 * 4)   // only hist + scalars need the memset

// Fragment-swizzled bf16 layout of X:
//   xs[ (row>>4)*2048 + (k>>3)*128 + (row&15)*8 + (k&7) ]
// An MFMA A/B fragment load (16 rows, k = s*32+quad*8..+7) is 64 lanes reading
// ONE CONTIGUOUS 1KB block -> coalesced global_load_dwordx4.

// Kernel 1: swizzled bf16 copy + fp32 squared norms + label histogram
// + zero-init of the per-row hp/hn atomics slots. (unchanged from round 4)
__global__ __launch_bounds__(256) void prep_kernel(
    const float* __restrict__ x, ushort* __restrict__ xs,
    float* __restrict__ sq, unsigned* __restrict__ hist,
    const int* __restrict__ lab,
    unsigned* __restrict__ hp_bits, unsigned* __restrict__ hn_comp, int N)
{
    const int tid = threadIdx.x;
    const int rbase = blockIdx.x * 32;
    const int rl = tid >> 4;           // row within 16-row group (0..15)
    const int kc = tid & 15;           // 8-elem k-chunk (0..15)

    #pragma unroll
    for (int g = 0; g < 2; ++g) {
        int row = rbase + g * 16 + rl;
        const float4* p = (const float4*)(x + (size_t)row * DK + kc * 8);
        float4 u = p[0], v = p[1];
        float f[8] = {u.x, u.y, u.z, u.w, v.x, v.y, v.z, v.w};
        union { bf16x8 v8; ushort us[8]; } o;
        float ps = 0.0f;
        #pragma unroll
        for (int e = 0; e < 8; ++e) {
            __hip_bfloat16 b = __float2bfloat16(f[e]);
            o.us[e] = *(ushort*)&b;
            ps += f[e] * f[e];
        }
        ((bf16x8*)xs)[(size_t)(row >> 4) * 256 + kc * 16 + rl] = o.v8;
        #pragma unroll
        for (int o2 = 8; o2 > 0; o2 >>= 1) ps += __shfl_xor(ps, o2, 16);
        if (kc == 0) {
            sq[row] = ps;
            hp_bits[row] = 0u;             // identity for max(d2p>=0)
            hn_comp[row] = 0u;             // ~bits identity for min-complement
            atomicAdd(&hist[lab[row]], 1u);
        }
    }
}

// ---- tile_kernel helpers ------------------------------------------------

// Load one 32-col B chunk: 8 coalesced b128 frag loads + sq/lab scalars.
#define LOADB(B, SQB, LB, CH)                                             \
    {                                                                     \
        const unsigned cb = (unsigned)cbegin + (unsigned)(CH) * 32;       \
        const ushort* bp = xs + (size_t)cb * DK + quad * 128 + m16 * 8;   \
        _Pragma("unroll")                                                 \
        for (int nt = 0; nt < 2; ++nt)                                    \
            _Pragma("unroll")                                             \
            for (int s = 0; s < 4; ++s)                                   \
                B[nt * 4 + s] = *(const bf16x8*)(bp + nt * 2048 + s * 512); \
        _Pragma("unroll")                                                 \
        for (int nt = 0; nt < 2; ++nt) {                                  \
            int colg = (int)cb + nt * 16 + m16;                           \
            SQB[nt] = sq[colg]; LB[nt] = lab[colg];                       \
        }                                                                 \
    }

// 16 MFMAs for one 32x32 output chunk; C=0 folded into s=0.
#define MFMA_CHUNK(B)                                                     \
    _Pragma("unroll")                                                     \
    for (int s = 0; s < 4; ++s)                                           \
        _Pragma("unroll")                                                 \
        for (int mt = 0; mt < 2; ++mt)                                    \
            _Pragma("unroll")                                             \
            for (int nt = 0; nt < 2; ++nt)                                \
                acc[mt][nt] = __builtin_amdgcn_mfma_f32_16x16x32_bf16(    \
                    afr[mt][s], B[nt * 4 + s],                            \
                    (s == 0) ? (f32x4){0.f, 0.f, 0.f, 0.f} : acc[mt][nt], \
                    0, 0, 0);

// masked max/min epilogue; fmaxf(fmaxf(.,.),.) fuses to v_max3/min3.
#define EPI_CHUNK(SQB, LB)                                                \
    _Pragma("unroll")                                                     \
    for (int mt = 0; mt < 2; ++mt)                                        \
        _Pragma("unroll")                                                 \
        for (int r = 0; r < 4; ++r) {                                     \
            int rl = rlv[mt][r];                                          \
            float t0 = fmaf(-2.0f, acc[mt][0][r], SQB[0]);                \
            float t1 = fmaf(-2.0f, acc[mt][1][r], SQB[1]);                \
            bool s0 = (rl == LB[0]);                                      \
            bool s1 = (rl == LB[1]);                                      \
            runhp[mt][r] = fmaxf(fmaxf(runhp[mt][r], s0 ? t0 : -BIGF),    \
                                 s1 ? t1 : -BIGF);                        \
            runhn[mt][r] = fminf(fminf(runhn[mt][r], s0 ? BIGF : t0),     \
                                 s1 ? BIGF : t1);                         \
        }

// Kernel 2: fused bf16-MFMA dist^2 tile + masked max/min in t = sqb - 2*dot.
// LDS-FREE, BARRIER-FREE restructure: each wave owns 32 rows x the full
// 512-col split. A-fragments (32 VGPR) are loaded from global ONCE and held
// in registers for the whole kernel (16x reuse) -- this removes the 2 MB/CU
// LDS re-read traffic (~10 us of LDS-pipe time) and all barriers, so the 4
// waves/SIMD drift in phase and cover each other's load latency. B streams
// from L1/L2 in 32-col chunks (8 coalesced b128), double-buffered: each
// chunk's loads issue ~MFMA+EPI (~240cy) ahead of consumption. A wave covers
// ALL cols of its rows -> no cross-wave reduce; atomics written directly.
// Peak live ~120 VGPR -> 128 step -> 4 waves/SIMD, 4 blocks/CU.
__global__ __launch_bounds__(256, 2) void tile_kernel(
    const ushort* __restrict__ xs, const float* __restrict__ sq,
    const int* __restrict__ lab,
    unsigned* __restrict__ hp_bits, unsigned* __restrict__ hn_comp, int N)
{
    const int tid  = threadIdx.x;
    const int lane = tid & 63;
    const int wave = tid >> 6;
    const int m16  = lane & 15;
    const int quad = lane >> 4;
    const int rbase  = blockIdx.x * 128 + wave * 32;
    const int cbegin = blockIdx.y * (N / NSPLIT);

    // A fragments: held in registers for the whole kernel (reused 16x)
    bf16x8 afr[2][4];
    {
        const ushort* ap = xs + (size_t)rbase * DK + quad * 128 + m16 * 8;
        #pragma unroll
        for (int mt = 0; mt < 2; ++mt)
            #pragma unroll
            for (int s = 0; s < 4; ++s)
                afr[mt][s] = *(const bf16x8*)(ap + mt * 2048 + s * 512);
    }

    // row labels for this lane's 8 output rows (broadcast int4 loads)
    int rlv[2][4];
    #pragma unroll
    for (int mt = 0; mt < 2; ++mt) {
        int4 v = *(const int4*)(lab + rbase + mt * 16 + quad * 4);
        rlv[mt][0] = v.x; rlv[mt][1] = v.y; rlv[mt][2] = v.z; rlv[mt][3] = v.w;
    }

    float runhp[2][4], runhn[2][4];
    #pragma unroll
    for (int mt = 0; mt < 2; ++mt)
        #pragma unroll
        for (int r = 0; r < 4; ++r) { runhp[mt][r] = -BIGF; runhn[mt][r] = BIGF; }

    bf16x8 bA[8], bB[8];
    float sqA[2], sqB[2];
    int lbA[2], lbB[2];
    f32x4 acc[2][2];

    LOADB(bA, sqA, lbA, 0);

    // 16 chunks of 32 cols; 2-chunk unrolled body keeps all indexing static.
    #pragma unroll 1
    for (int k = 0; k < 16; k += 2) {
        LOADB(bB, sqB, lbB, k + 1);         // in flight under MFMA+EPI of bA
        MFMA_CHUNK(bA);
        EPI_CHUNK(sqA, lbA);
        LOADB(bA, sqA, lbA, (k + 2 < 16) ? k + 2 : 15);  // clamped: redundant on last
        MFMA_CHUNK(bB);
        EPI_CHUNK(sqB, lbB);
    }

    // reduce across the 16 m16-lanes (cols) sharing each row
    #pragma unroll
    for (int mt = 0; mt < 2; ++mt)
        #pragma unroll
        for (int r = 0; r < 4; ++r) {
            #pragma unroll
            for (int o = 8; o > 0; o >>= 1) {
                runhp[mt][r] = fmaxf(runhp[mt][r], __shfl_xor(runhp[mt][r], o, 16));
                runhn[mt][r] = fminf(runhn[mt][r], __shfl_xor(runhn[mt][r], o, 16));
            }
        }

    if (m16 == 0) {
        #pragma unroll
        for (int mt = 0; mt < 2; ++mt)
            #pragma unroll
            for (int r = 0; r < 4; ++r) {
                int row = rbase + mt * 16 + quad * 4 + r;
                float sqa = sq[row];
                float d2p = fmaxf(sqa + runhp[mt][r], 0.0f);  // == ref's max(d2,0)
                float d2n = fmaxf(sqa + runhn[mt][r], 0.0f);
                atomicMax(&hp_bits[row], __float_as_uint(d2p));
                atomicMax(&hn_comp[row], ~__float_as_uint(d2n));  // min via complement
            }
    }
}

// Kernel 3: per-row loss + grid reduction; last block writes the scalar.
__global__ void finalize_kernel(const unsigned* __restrict__ hp_bits,
                                const unsigned* __restrict__ hn_comp,
                                const int* __restrict__ lab,
                                const unsigned* __restrict__ hist,
                                float* __restrict__ gsum, float* __restrict__ gcnt,
                                unsigned* __restrict__ bcount,
                                float* __restrict__ out, int N)
{
    __shared__ float s_sum[256];
    __shared__ float s_cnt[256];
    int tid = threadIdx.x;
    int row = blockIdx.x * 256 + tid;
    float loss = 0.0f, cv = 0.0f;
    if (row < N) {
        unsigned c = hist[lab[row]];
        bool valid = (c >= 2u) && (c < (unsigned)N);
        if (valid) {
            float dp = sqrtf(__uint_as_float(hp_bits[row]));
            float dn = sqrtf(__uint_as_float(~hn_comp[row]));
            loss = fmaxf(dp - dn + MARGIN, 0.0f);
            cv = 1.0f;
        }
    }
    s_sum[tid] = loss; s_cnt[tid] = cv;
    __syncthreads();
    for (int o = 128; o > 0; o >>= 1) {
        if (tid < o) { s_sum[tid] += s_sum[tid + o]; s_cnt[tid] += s_cnt[tid + o]; }
        __syncthreads();
    }
    if (tid == 0) {
        atomicAdd(gsum, s_sum[0]);
        atomicAdd(gcnt, s_cnt[0]);
        __threadfence();
        unsigned old = atomicAdd(bcount, 1u);
        if (old == gridDim.x - 1) {
            float s = atomicAdd(gsum, 0.0f);   // coherent read
            float c = atomicAdd(gcnt, 0.0f);
            out[0] = (c > 0.0f) ? s / c : 0.0f;
        }
    }
}

extern "C" void kernel_launch(void* const* d_in, const int* in_sizes, int n_in,
                              void* d_out, int out_size, void* d_ws, size_t ws_size,
                              hipStream_t stream) {
    const float* x = (const float*)d_in[0];
    const int* lab = (const int*)d_in[1];
    float* out = (float*)d_out;
    const int N = in_sizes[1];          // 8192

    unsigned* ws = (unsigned*)d_ws;
    unsigned* hist    = ws + WS_HIST;
    float* gsum = (float*)(ws + WS_GSUM);
    float* gcnt = (float*)(ws + WS_GCNT);
    unsigned* bcount = ws + WS_BCNT;
    unsigned* hp_bits = ws + WS_HP;
    unsigned* hn_comp = ws + WS_HN;
    float* sq = (float*)(ws + WS_SQ);
    ushort* xs = (ushort*)(ws + WS_XB);

    hipMemsetAsync(d_ws, 0, (size_t)WS_ZERO_BYTES, stream);
    prep_kernel<<<N / 32, 256, 0, stream>>>(x, xs, sq, hist, lab, hp_bits, hn_comp, N);
    dim3 grid(N / 128, NSPLIT);
    tile_kernel<<<grid, 256, 0, stream>>>(xs, sq, lab, hp_bits, hn_comp, N);
    finalize_kernel<<<N / 256, 256, 0, stream>>>(hp_bits, hn_comp, lab, hist,
                                                 gsum, gcnt, bcount, out, N);
}